// Round 3
// baseline (409.198 us; speedup 1.0000x reference)
//
#include <hip/hip_runtime.h>
#include <math.h>

#define BB 4
#define CC 128
#define BT 32
#define NBOX 4
#define HH 256
#define WW 256
#define HW (HH*WW)
#define SP 257
#define SPLANE (SP*SP)
#define NPLANE (BB*BT)          // 128 integral-image planes
#define CHUNK 32                // rows per column-scan chunk
#define NCHUNK (HH/CHUNK)       // 8

// ---------------- Kernel A: 1x1 conv (128->32) + BN1 + row cumsum, fused ----------------
// Block = one image row (b,i), 256 threads (thread = column j).
__global__ __launch_bounds__(256) void conv_bn1_rowscan(
        const float* __restrict__ x, const float* __restrict__ w1,
        const float* __restrict__ g1, const float* __restrict__ b1,
        const float* __restrict__ m1, const float* __restrict__ v1,
        float* __restrict__ h) {
    __shared__ float w1s[CC * BT];      // 16 KB, layout [k][c] as in global
    __shared__ float wtot[BT * 4];      // per-k wave totals
    int b = blockIdx.x >> 8;
    int i = blockIdx.x & 255;
    int j = threadIdx.x;
    int wv = threadIdx.x >> 6;
    int lane = threadIdx.x & 63;

    // stage w1 into LDS (linear, coalesced)
    #pragma unroll
    for (int t = 0; t < CC * BT / 256; ++t)
        w1s[t * 256 + j] = w1[t * 256 + j];
    __syncthreads();

    const float* xb = x + (size_t)b * (CC * HW) + i * WW + j;
    float acc[BT];
    #pragma unroll
    for (int k = 0; k < BT; ++k) acc[k] = 0.f;
    #pragma unroll 4
    for (int c = 0; c < CC; ++c) {
        float xv = xb[(size_t)c * HW];
        #pragma unroll
        for (int k = 0; k < BT; ++k)
            acc[k] = fmaf(xv, w1s[k * CC + c], acc[k]);   // uniform addr -> broadcast
    }

    // BN1 + per-wave inclusive scan over j for each channel
    #pragma unroll
    for (int k = 0; k < BT; ++k) {
        float inv = g1[k] * __frsqrt_rn(v1[k] + 1e-5f);
        float s = acc[k] * inv + (b1[k] - m1[k] * inv);
        #pragma unroll
        for (int off = 1; off < 64; off <<= 1) {
            float o = __shfl_up(s, off, 64);
            if (lane >= off) s += o;
        }
        acc[k] = s;
        if (lane == 63) wtot[k * 4 + wv] = s;
    }
    __syncthreads();

    // add prefix of earlier waves' totals, store
    float* hb = h + (size_t)b * (BT * HW) + i * WW + j;
    #pragma unroll
    for (int k = 0; k < BT; ++k) {
        float off = 0.f;
        for (int ww = 0; ww < wv; ++ww) off += wtot[k * 4 + ww];
        hb[(size_t)k * HW] = acc[k] + off;
    }
}

// ---------------- Kernel B2a: per-chunk column partial sums ----------------
__global__ __launch_bounds__(256) void col_partial(const float* __restrict__ t,
                                                   float* __restrict__ T) {
    int plane = blockIdx.x >> 3;
    int chunk = blockIdx.x & 7;
    int j = threadIdx.x;
    const float* tp = t + (size_t)plane * HW + chunk * CHUNK * WW + j;
    float s = 0.f;
    #pragma unroll 8
    for (int r = 0; r < CHUNK; ++r) s += tp[r * WW];
    T[blockIdx.x * 256 + j] = s;
}

// ---------------- Kernel B2b: column scan with chunk offsets -> padded S ----------------
__global__ __launch_bounds__(256) void col_final(const float* __restrict__ t,
                                                 const float* __restrict__ T,
                                                 float* __restrict__ s) {
    int plane = blockIdx.x >> 3;
    int chunk = blockIdx.x & 7;
    int j = threadIdx.x;
    float off = 0.f;
    for (int c = 0; c < chunk; ++c) off += T[(plane * 8 + c) * 256 + j];
    const float* tp = t + (size_t)plane * HW + chunk * CHUNK * WW + j;
    float* sp = s + (size_t)plane * SPLANE;
    if (chunk == 0) {                    // top padding row
        sp[j + 1] = 0.f;
        if (j == 0) sp[0] = 0.f;
    }
    float run = off;
    int rowbase = chunk * CHUNK;
    #pragma unroll 4
    for (int r = 0; r < CHUNK; ++r) {
        run += tp[r * WW];
        sp[(size_t)(rowbase + r + 1) * SP + j + 1] = run;
        if (j == 0) sp[(size_t)(rowbase + r + 1) * SP] = 0.f;   // left padding col
    }
}

// ---------------- Kernel C: box sample + BN2 + relus ----------------
// Block = 4 rows of one (b,k,n); wave w -> row i4*4+w; lane covers 4 cols at stride 64.
__global__ __launch_bounds__(256) void box_sample(
        const float* __restrict__ s, const float* __restrict__ x,
        const float* __restrict__ xmin, const float* __restrict__ xmax,
        const float* __restrict__ ymin, const float* __restrict__ ymax,
        const float* __restrict__ g2, const float* __restrict__ b2,
        const float* __restrict__ m2, const float* __restrict__ v2,
        float* __restrict__ out) {
    __shared__ float D[4][SP];
    int bid = blockIdx.x;
    int wv = threadIdx.x >> 6;
    int l = threadIdx.x & 63;
    int i = (bid & 63) * 4 + wv;
    int n = (bid >> 6) & 3;
    int k = (bid >> 8) & 31;
    int b = bid >> 13;
    int kn = k * NBOX + n;
    const float* sp = s + (size_t)(b * BT + k) * SPLANE;

    float xmn = xmin[kn], xmx = xmax[kn], ymn = ymin[kn], ymx = ymax[kn];

    // vertical interpolation (wave-uniform)
    float u_hi = fminf(fmaxf((float)i + xmx, 0.f), 256.f);
    float u_lo = fminf(fmaxf((float)i + xmn, 0.f), 256.f);
    int i1 = (int)fminf(floorf(u_hi), 255.f);
    int i0 = (int)fminf(floorf(u_lo), 255.f);
    float wu1 = u_hi - (float)i1;
    float wu0 = u_lo - (float)i0;

    const float* rA = sp + (size_t)i1 * SP;
    const float* rB = rA + SP;
    const float* rC = sp + (size_t)i0 * SP;
    const float* rD = rC + SP;

    // D[v] = rowHi(v) - rowLo(v); coalesced stride-64 loads
    #pragma unroll
    for (int c = 0; c < 4; ++c) {
        int v = l + 64 * c;
        float a = rA[v], bb = rB[v], cc = rC[v], dd = rD[v];
        D[wv][v] = (a + wu1 * (bb - a)) - (cc + wu0 * (dd - cc));
    }
    if (l == 0) {
        float a = rA[256], bb = rB[256], cc = rC[256], dd = rD[256];
        D[wv][256] = (a + wu1 * (bb - a)) - (cc + wu0 * (dd - cc));
    }
    __syncthreads();

    float inv = g2[kn] * __frsqrt_rn(v2[kn] + 1e-3f);
    float scale = inv * __frcp_rn((xmx - xmn) * (ymx - ymn));
    float add = b2[kn] - m2[kn] * inv;
    size_t obase = ((size_t)(b * CC + kn) * HH + i) * WW;

    #pragma unroll
    for (int c = 0; c < 4; ++c) {
        int j = l + 64 * c;
        float v_hi = fminf(fmaxf((float)j + ymx, 0.f), 256.f);
        float v_lo = fminf(fmaxf((float)j + ymn, 0.f), 256.f);
        int j1 = (int)fminf(floorf(v_hi), 255.f);
        int j0 = (int)fminf(floorf(v_lo), 255.f);
        float wv1 = v_hi - (float)j1;
        float wv0 = v_lo - (float)j0;
        float dh = D[wv][j1], dh1 = D[wv][j1 + 1];
        float dl = D[wv][j0], dl1 = D[wv][j0 + 1];
        float hi = dh + wv1 * (dh1 - dh);
        float lo = dl + wv0 * (dl1 - dl);
        float val = fmaxf((hi - lo) * scale + add, 0.f);
        out[obase + j] = fmaxf(x[obase + j] + val, 0.f);
    }
}

extern "C" void kernel_launch(void* const* d_in, const int* in_sizes, int n_in,
                              void* d_out, int out_size, void* d_ws, size_t ws_size,
                              hipStream_t stream) {
    const float* x    = (const float*)d_in[0];
    const float* w1   = (const float*)d_in[1];
    const float* g1   = (const float*)d_in[2];
    const float* b1   = (const float*)d_in[3];
    const float* m1   = (const float*)d_in[4];
    const float* v1   = (const float*)d_in[5];
    const float* xmin = (const float*)d_in[6];
    const float* xmax = (const float*)d_in[7];
    const float* ymin = (const float*)d_in[8];
    const float* ymax = (const float*)d_in[9];
    const float* g2   = (const float*)d_in[10];
    const float* b2   = (const float*)d_in[11];
    const float* m2   = (const float*)d_in[12];
    const float* v2   = (const float*)d_in[13];
    float* out = (float*)d_out;

    float* h = (float*)d_ws;                        // B*BT*HW floats (33.5 MB)
    float* S = h + (size_t)BB * BT * HW;            // NPLANE*SPLANE floats (33.8 MB)
    float* T = S + (size_t)NPLANE * SPLANE;         // NPLANE*NCHUNK*256 floats (1 MB)

    conv_bn1_rowscan<<<BB * HH, 256, 0, stream>>>(x, w1, g1, b1, m1, v1, h);
    col_partial<<<NPLANE * NCHUNK, 256, 0, stream>>>(h, T);
    col_final  <<<NPLANE * NCHUNK, 256, 0, stream>>>(h, T, S);
    box_sample <<<BB * BT * NBOX * HH / 4, 256, 0, stream>>>(S, x, xmin, xmax, ymin, ymax,
                                                             g2, b2, m2, v2, out);
}